// Round 10
// baseline (920.029 us; speedup 1.0000x reference)
//
#include <hip/hip_runtime.h>
#include <hip/hip_bf16.h>

#define BATCH   2048
#define NPAR    256
#define NF      32
#define NG      16
#define NBR     4
#define OFS     262144
#define DOUT    128
#define NROWSX  (OFS + NPAR*BATCH)     // 786432 rows of x
#define MROWS   (NPAR*BATCH)           // 524288 parent rows
#define CHBASE  (NROWSX*NF)            // float offset of children region in out
#define NMLP    512                    // MLP blocks: 8 waves x 8 tiles (rolled)
#define NT      8                      // tiles per wave
#define NCOPY   1536                   // copy blocks
#define CPN4    (NROWSX*NF/4)          // 6291456 float4 to copy

typedef short bf16x8 __attribute__((ext_vector_type(8)));   // 8 bf16 bit-patterns
typedef float f32x4  __attribute__((ext_vector_type(4)));

// ws layout (bytes): [0,1MB) G1 f32 | +32KB W2frag | +8KB W1frag | +8KB Rfrag
#define WSOFF_W2F  1048576
#define WSOFF_W1F  (1048576 + 32768)
#define WSOFF_RF   (1048576 + 32768 + 8192)

__device__ __forceinline__ unsigned short f2bf(float f){
  unsigned int u = __float_as_uint(f);
  u += 0x7FFFu + ((u >> 16) & 1u);          // RNE
  return (unsigned short)(u >> 16);
}

// blocks [0,1024): G1[e][j] = b1[j] + sum_k global[e][k] * W1[32+k][j]
// blocks [1024,1036): pack W2 / W1-feature-half / repeat-matrix R fragments.
__global__ void k_prep(const float* __restrict__ gf, const float* __restrict__ W1,
                       const float* __restrict__ b1, const float* __restrict__ W2,
                       char* __restrict__ ws){
  int bid = blockIdx.x, tid = threadIdx.x;
  if (bid < 1024){
    int idx = bid*256 + tid;
    int e = idx >> 7, j = idx & 127;
    float s = b1[j];
    const float* grow = gf + e*NG;
    const float* w = W1 + NF*DOUT + j;
    #pragma unroll
    for (int k = 0; k < NG; k++) s = fmaf(grow[k], w[k*DOUT], s);
    ((float*)ws)[idx] = s;
    return;
  }
  int t = (bid - 1024)*256 + tid;          // 0..3071
  if (t < 2048){
    // W2 fragment uint4 t: f = t>>6 (kk*8+n), lane l = t&63
    int f = t >> 6, l = t & 63;
    int kk = f >> 3, n = f & 7;
    int krow = 32*kk + 8*(l >> 4);
    int col  = 16*n + (l & 15);
    union { uint4 q; unsigned short u[8]; } w;
    #pragma unroll
    for (int e = 0; e < 8; e++) w.u[e] = f2bf(W2[(krow + e)*DOUT + col]);
    ((uint4*)(ws + WSOFF_W2F))[t] = w.q;
  } else if (t < 2560){
    int q = t - 2048;                      // 0..511: W1 feature-half fragments
    int n = q >> 6, l = q & 63;
    int kb = 8*(l >> 4);
    int col = 16*n + (l & 15);
    union { uint4 v; unsigned short u[8]; } w;
    #pragma unroll
    for (int e = 0; e < 8; e++) w.u[e] = f2bf(W1[(kb + e)*DOUT + col]);
    ((uint4*)(ws + WSOFF_W1F))[q] = w.v;
  } else {
    // R fragments: A[r][k] = 1 iff k == 4n + (r>>2)  (repeat_interleave matrix)
    int q = t - 2560;                      // 0..511
    int n = q >> 6, l = q & 63;
    int g = l >> 4, r = l & 15;
    int e1 = 4*n + (r >> 2) - 8*g;
    union { uint4 v; unsigned short u[8]; } w;
    #pragma unroll
    for (int e = 0; e < 8; e++) w.u[e] = (e == e1) ? 0x3F80 : 0;
    ((uint4*)(ws + WSOFF_RF))[q] = w.v;
  }
}

// Main kernel, 512 threads, no occupancy hints.
// bid%4==0 -> MLP block (8 waves x NT rolled tiles); else copy block.
__global__ void k_main(
    const float* __restrict__ x, const int* __restrict__ pidx,
    const float* __restrict__ b2, const char* __restrict__ ws,
    float* __restrict__ out)
{
  __shared__ uint4 sB2[2048];   // 32 KB: W2 B-fragments [frag(kk*8+n)][lane]
  __shared__ uint4 sWR[1024];   // 16 KB: [0,512) W1 frags, [512,1024) R frags
  __shared__ uint4 sH1[2048];   // 32 KB: per-wave 4KB h1 tile (bf16, swizzled)

  const int bid = blockIdx.x;
  const int tid = threadIdx.x;

  if (bid % 4){
    // ---- copy path: out[0:NROWSX*NF] = x, pure bandwidth, free-running ----
    const int cid = (bid/4)*3 + (bid % 4) - 1;    // 0..NCOPY-1
    const float4* src4 = (const float4*)x;
    float4* dst4 = (float4*)out;
    for (int i = cid*512 + tid; i < CPN4; i += NCOPY*512)
      dst4[i] = src4[i];
    return;
  }
  const int mid = bid/4;                   // 0..NMLP-1

  // ---- stage pre-packed fragments into LDS (6 x 16B per thread) ----
  const uint4* W2f = (const uint4*)(ws + WSOFF_W2F);
  const uint4* WRf = (const uint4*)(ws + WSOFF_W1F);  // W1+R contiguous, 1024
  #pragma unroll
  for (int i = 0; i < 4; i++) sB2[i*512 + tid] = W2f[i*512 + tid];
  sWR[tid] = WRf[tid];                   // W1 fragments
  sWR[512 + tid] = WRf[512 + tid];       // R fragments
  __syncthreads();

  const int lane = tid & 63;
  const int wv   = tid >> 6;
  const int r15  = lane & 15;
  const int g    = lane >> 4;
  const float* G1 = (const float*)ws;

  char* h1base = (char*)sH1 + wv*4096;
  const bf16x8* B2f = (const bf16x8*)sB2;
  const bf16x8* B1f = (const bf16x8*)sWR;          // frags 0..7
  const bf16x8* Rf  = (const bf16x8*)(sWR + 512);  // frags 0..7

  const int w = mid*8 + wv;     // global wave id: tiles w*NT .. w*NT+NT-1

  #pragma unroll 1
  for (int t = 0; t < NT; t++){
    const int row0 = (w*NT + t)*16;

    // This lane's batch row within the tile is r15 (transposed layout).
    const int idxA = pidx[row0 + r15];         // L1-hot after t=0

    // x row: A/B fragment source (cols 8g..8g+7)
    const float* ap = x + idxA*NF + 8*g;
    float4 a0 = *(const float4*)ap;
    float4 a1 = *(const float4*)(ap + 4);

    // GEMM1 acc init: G1 row (bias + global half folded in), float4 loads
    const int g1r = idxA & (BATCH-1);
    f32x4 acc1[8];
    #pragma unroll
    for (int n = 0; n < 8; n++)
      acc1[n] = *(const f32x4*)(G1 + g1r*DOUT + 16*n + 4*g);

    // convert A-fragment
    union { bf16x8 v; __hip_bfloat162 h[4]; } af;
    af.h[0] = __float22bfloat162_rn(make_float2(a0.x, a0.y));
    af.h[1] = __float22bfloat162_rn(make_float2(a0.z, a0.w));
    af.h[2] = __float22bfloat162_rn(make_float2(a1.x, a1.y));
    af.h[3] = __float22bfloat162_rn(make_float2(a1.z, a1.w));

    // GEMM1 (transposed): acc1[n][r] = h1[row_r15][16n+4g+r]
    #pragma unroll
    for (int n = 0; n < 8; n++)
      acc1[n] = __builtin_amdgcn_mfma_f32_16x16x32_bf16(B1f[n*64 + lane], af.v, acc1[n], 0, 0, 0);

    // leaky-relu, pack, ds_write_b64 into swizzled wave-private [16][128] tile
    #pragma unroll
    for (int n = 0; n < 8; n++){
      float v0 = acc1[n][0], v1 = acc1[n][1], v2 = acc1[n][2], v3 = acc1[n][3];
      v0 = v0 > 0.f ? v0 : 0.01f*v0;
      v1 = v1 > 0.f ? v1 : 0.01f*v1;
      v2 = v2 > 0.f ? v2 : 0.01f*v2;
      v3 = v3 > 0.f ? v3 : 0.01f*v3;
      union { uint2 q; __hip_bfloat162 h[2]; } pk;
      pk.h[0] = __float22bfloat162_rn(make_float2(v0, v1));
      pk.h[1] = __float22bfloat162_rn(make_float2(v2, v3));
      int off = r15*256 + (16*n + 4*g)*2;
      off ^= (r15 & 7) << 4;
      *(uint2*)(h1base + off) = pk.q;
    }
    // wave-private LDS tile: compiler orders via lgkmcnt; no barrier needed.

    // GEMM2: b2 folded into init, residual folded in via R-fragment MFMA
    f32x4 acc2[8];
    #pragma unroll
    for (int n = 0; n < 8; n++)
      acc2[n] = *(const f32x4*)(b2 + 16*n + 4*g);
    #pragma unroll
    for (int n = 0; n < 8; n++)
      acc2[n] = __builtin_amdgcn_mfma_f32_16x16x32_bf16(Rf[n*64 + lane], af.v, acc2[n], 0, 0, 0);
    #pragma unroll
    for (int kk = 0; kk < 4; kk++){
      int roff = r15*256 + 64*kk + 16*g;
      roff ^= (r15 & 7) << 4;
      bf16x8 a2 = *(const bf16x8*)(h1base + roff);
      #pragma unroll
      for (int n = 0; n < 8; n++)
        acc2[n] = __builtin_amdgcn_mfma_f32_16x16x32_bf16(B2f[(kk*8 + n)*64 + lane], a2, acc2[n], 0, 0, 0);
    }

    // epilogue: pure float4 stores to children layout (no trailing loads)
    const int p  = row0 >> 11;             // parent (span never crosses parents)
    const int b0 = row0 & (BATCH-1);
    const int orow = CHBASE + ((p*NBR)*BATCH + b0 + r15)*NF;
    #pragma unroll
    for (int n = 0; n < 8; n++){
      int c0 = 16*n + 4*g;                 // first of 4 consecutive output cols
      int br = c0 >> 5, fc0 = c0 & 31;
      *(f32x4*)(out + orow + br*(BATCH*NF) + fc0) = acc2[n];
    }
  }
}

extern "C" void kernel_launch(void* const* d_in, const int* in_sizes, int n_in,
                              void* d_out, int out_size, void* d_ws, size_t ws_size,
                              hipStream_t stream){
  const float* x   = (const float*)d_in[0];
  const float* gf  = (const float*)d_in[1];
  const int*   pidx= (const int*)d_in[2];
  const float* W1  = (const float*)d_in[3];
  const float* b1  = (const float*)d_in[4];
  const float* W2  = (const float*)d_in[5];
  const float* b2  = (const float*)d_in[6];
  float* out = (float*)d_out;
  char* ws   = (char*)d_ws;               // 1MB G1 + 48KB packed fragments

  k_prep<<<1036, 256, 0, stream>>>(gf, W1, b1, W2, ws);
  k_main<<<NMLP + NCOPY, 512, 0, stream>>>(x, pidx, b2, ws, out);
}

// Round 12
// 167.585 us; speedup vs baseline: 5.4899x; 5.4899x over previous
//
#include <hip/hip_runtime.h>
#include <hip/hip_bf16.h>

#define BATCH   2048
#define NPAR    256
#define NF      32
#define NG      16
#define NBR     4
#define OFS     262144
#define DOUT    128
#define NROWSX  (OFS + NPAR*BATCH)     // 786432 rows of x
#define MROWS   (NPAR*BATCH)           // 524288 parent rows
#define CHBASE  (NROWSX*NF)            // float offset of children region in out
#define NMLP    2048                   // MLP blocks: 4 waves x 4 tiles = 16 tiles
#define NCOPY   1024                   // copy blocks
#define CPN4    (NROWSX*NF/4)          // 6291456 float4 to copy

typedef short bf16x8 __attribute__((ext_vector_type(8)));   // 8 bf16 bit-patterns
typedef float f32x4  __attribute__((ext_vector_type(4)));

// ws layout (bytes): [0,1MB) G1 f32 | +32KB W2frag | +8KB W1frag | +8KB Rfrag
#define WSOFF_W2F  1048576
#define WSOFF_W1F  (1048576 + 32768)
#define WSOFF_RF   (1048576 + 32768 + 8192)

__device__ __forceinline__ unsigned short f2bf(float f){
  unsigned int u = __float_as_uint(f);
  u += 0x7FFFu + ((u >> 16) & 1u);          // RNE
  return (unsigned short)(u >> 16);
}

// blocks [0,1024): G1[e][j] = b1[j] + sum_k global[e][k] * W1[32+k][j]
// blocks [1024,1036): pack W2 / W1-feature-half / repeat-matrix R fragments.
__global__ void k_prep(const float* __restrict__ gf, const float* __restrict__ W1,
                       const float* __restrict__ b1, const float* __restrict__ W2,
                       char* __restrict__ ws){
  int bid = blockIdx.x, tid = threadIdx.x;
  if (bid < 1024){
    int idx = bid*256 + tid;
    int e = idx >> 7, j = idx & 127;
    float s = b1[j];
    const float* grow = gf + e*NG;
    const float* w = W1 + NF*DOUT + j;
    #pragma unroll
    for (int k = 0; k < NG; k++) s = fmaf(grow[k], w[k*DOUT], s);
    ((float*)ws)[idx] = s;
    return;
  }
  int t = (bid - 1024)*256 + tid;          // 0..3071
  if (t < 2048){
    // W2 fragment uint4 t: f = t>>6 (kk*8+n), lane l = t&63
    int f = t >> 6, l = t & 63;
    int kk = f >> 3, n = f & 7;
    int krow = 32*kk + 8*(l >> 4);
    int col  = 16*n + (l & 15);
    union { uint4 q; unsigned short u[8]; } w;
    #pragma unroll
    for (int e = 0; e < 8; e++) w.u[e] = f2bf(W2[(krow + e)*DOUT + col]);
    ((uint4*)(ws + WSOFF_W2F))[t] = w.q;
  } else if (t < 2560){
    int q = t - 2048;                      // 0..511: W1 feature-half fragments
    int n = q >> 6, l = q & 63;
    int kb = 8*(l >> 4);
    int col = 16*n + (l & 15);
    union { uint4 v; unsigned short u[8]; } w;
    #pragma unroll
    for (int e = 0; e < 8; e++) w.u[e] = f2bf(W1[(kb + e)*DOUT + col]);
    ((uint4*)(ws + WSOFF_W1F))[q] = w.v;
  } else {
    // R fragments: A[r][k] = 1 iff k == 4n + (r>>2)  (repeat_interleave matrix)
    int q = t - 2560;                      // 0..511
    int n = q >> 6, l = q & 63;
    int g = l >> 4, r = l & 15;
    int e1 = 4*n + (r >> 2) - 8*g;
    union { uint4 v; unsigned short u[8]; } w;
    #pragma unroll
    for (int e = 0; e < 8; e++) w.u[e] = (e == e1) ? 0x3F80 : 0;
    ((uint4*)(ws + WSOFF_RF))[q] = w.v;
  }
}

// Main kernel, 256 threads (4 waves) — 256-thd blocks compile to ~160 VGPR
// (round-2 evidence), avoiding the 64-VGPR pin that spills 512-thd kernels.
// Grid MUST be exactly NMLP+NCOPY=3072: bid%3==2 -> copy (cid=bid/3 in
// [0,1024)); bid%3 in {0,1} -> MLP with mid=(bid/3)*2+(bid%3) in [0,2048).
__global__ void k_main(
    const float* __restrict__ x, const int* __restrict__ pidx,
    const float* __restrict__ b2, const char* __restrict__ ws,
    float* __restrict__ out)
{
  __shared__ uint4 sB2[2048];   // 32 KB: W2 B-fragments [frag(kk*8+n)][lane]
  __shared__ uint4 sWR[1024];   // 16 KB: [0,512) W1 frags, [512,1024) R frags
  __shared__ uint4 sH1[1024];   // 16 KB: per-wave 4KB h1 tile (bf16, swizzled)

  const int bid = blockIdx.x;
  const int tid = threadIdx.x;

  if (bid % 3 == 2){
    // ---- copy path: out[0:NROWSX*NF] = x, pure bandwidth, free-running ----
    const int cid = bid / 3;                      // 0..NCOPY-1
    const float4* src4 = (const float4*)x;
    float4* dst4 = (float4*)out;
    for (int i = cid*256 + tid; i < CPN4; i += NCOPY*256)
      dst4[i] = src4[i];
    return;
  }
  const int mid = (bid/3)*2 + (bid % 3);          // 0..NMLP-1

  // ---- stage pre-packed fragments into LDS (12 x 16B per thread) ----
  const uint4* W2f = (const uint4*)(ws + WSOFF_W2F);
  const uint4* WRf = (const uint4*)(ws + WSOFF_W1F);  // W1+R contiguous, 1024
  #pragma unroll
  for (int i = 0; i < 8; i++) sB2[i*256 + tid] = W2f[i*256 + tid];
  #pragma unroll
  for (int i = 0; i < 4; i++) sWR[i*256 + tid] = WRf[i*256 + tid];
  __syncthreads();

  const int lane = tid & 63;
  const int wv   = tid >> 6;
  const int r15  = lane & 15;
  const int g    = lane >> 4;
  const float* G1 = (const float*)ws;

  char* h1base = (char*)sH1 + wv*4096;
  const bf16x8* B2f = (const bf16x8*)sB2;
  const bf16x8* B1f = (const bf16x8*)sWR;          // frags 0..7
  const bf16x8* Rf  = (const bf16x8*)(sWR + 512);  // frags 0..7

  const int tbase = mid*16 + wv*4;    // this wave's 4 consecutive tiles

  // tile 0 gather chain starts immediately
  int idxA = pidx[tbase*16 + r15];
  const float* ap = x + idxA*NF + 8*g;
  float4 a0 = *(const float4*)ap;
  float4 a1 = *(const float4*)(ap + 4);

  #pragma unroll
  for (int t = 0; t < 4; t++){
    const int row0 = (tbase + t)*16;

    // prefetch next tile's index (carried; clamped re-load on t=3)
    const int tn = (t < 3) ? t+1 : 3;
    const int idxn = pidx[(tbase + tn)*16 + r15];

    // GEMM1 acc init: G1 row (bias + global half), issues early
    const int g1r = idxA & (BATCH-1);
    f32x4 acc1[8];
    #pragma unroll
    for (int n = 0; n < 8; n++)
      acc1[n] = *(const f32x4*)(G1 + g1r*DOUT + 16*n + 4*g);

    // convert A-fragment (cols 8g..8g+7 of this lane's batch row)
    union { bf16x8 v; __hip_bfloat162 h[4]; } af;
    af.h[0] = __float22bfloat162_rn(make_float2(a0.x, a0.y));
    af.h[1] = __float22bfloat162_rn(make_float2(a0.z, a0.w));
    af.h[2] = __float22bfloat162_rn(make_float2(a1.x, a1.y));
    af.h[3] = __float22bfloat162_rn(make_float2(a1.z, a1.w));

    // GEMM1 (transposed): acc1[n][r] = h1[row_r15][16n+4g+r]
    #pragma unroll
    for (int n = 0; n < 8; n++)
      acc1[n] = __builtin_amdgcn_mfma_f32_16x16x32_bf16(B1f[n*64 + lane], af.v, acc1[n], 0, 0, 0);

    // next x-row loads (independent; hide under MFMA1/pack)
    const float* apn = x + idxn*NF + 8*g;
    float4 a0n = *(const float4*)apn;
    float4 a1n = *(const float4*)(apn + 4);

    // leaky-relu, pack, ds_write_b64 into swizzled wave-private [16][128] tile
    #pragma unroll
    for (int n = 0; n < 8; n++){
      float v0 = acc1[n][0], v1 = acc1[n][1], v2 = acc1[n][2], v3 = acc1[n][3];
      v0 = v0 > 0.f ? v0 : 0.01f*v0;
      v1 = v1 > 0.f ? v1 : 0.01f*v1;
      v2 = v2 > 0.f ? v2 : 0.01f*v2;
      v3 = v3 > 0.f ? v3 : 0.01f*v3;
      union { uint2 q; __hip_bfloat162 h[2]; } pk;
      pk.h[0] = __float22bfloat162_rn(make_float2(v0, v1));
      pk.h[1] = __float22bfloat162_rn(make_float2(v2, v3));
      int off = r15*256 + (16*n + 4*g)*2;
      off ^= (r15 & 7) << 4;
      *(uint2*)(h1base + off) = pk.q;
    }
    // wave-private LDS tile: compiler orders via lgkmcnt; no barrier needed.

    // GEMM2: b2 folded into init, residual folded in via R-fragment MFMA
    f32x4 acc2[8];
    #pragma unroll
    for (int n = 0; n < 8; n++)
      acc2[n] = *(const f32x4*)(b2 + 16*n + 4*g);
    #pragma unroll
    for (int n = 0; n < 8; n++)
      acc2[n] = __builtin_amdgcn_mfma_f32_16x16x32_bf16(Rf[n*64 + lane], af.v, acc2[n], 0, 0, 0);
    #pragma unroll
    for (int kk = 0; kk < 4; kk++){
      int roff = r15*256 + 64*kk + 16*g;
      roff ^= (r15 & 7) << 4;
      bf16x8 a2 = *(const bf16x8*)(h1base + roff);
      #pragma unroll
      for (int n = 0; n < 8; n++)
        acc2[n] = __builtin_amdgcn_mfma_f32_16x16x32_bf16(B2f[(kk*8 + n)*64 + lane], a2, acc2[n], 0, 0, 0);
    }

    // epilogue: pure float4 stores to children layout (no trailing loads)
    const int p  = row0 >> 11;             // parent (64-row span never crosses)
    const int b0 = row0 & (BATCH-1);
    const int orow = CHBASE + ((p*NBR)*BATCH + b0 + r15)*NF;
    #pragma unroll
    for (int n = 0; n < 8; n++){
      int c0 = 16*n + 4*g;                 // first of 4 consecutive output cols
      int br = c0 >> 5, fc0 = c0 & 31;
      *(f32x4*)(out + orow + br*(BATCH*NF) + fc0) = acc2[n];
    }

    idxA = idxn; a0 = a0n; a1 = a1n;
  }
}

extern "C" void kernel_launch(void* const* d_in, const int* in_sizes, int n_in,
                              void* d_out, int out_size, void* d_ws, size_t ws_size,
                              hipStream_t stream){
  const float* x   = (const float*)d_in[0];
  const float* gf  = (const float*)d_in[1];
  const int*   pidx= (const int*)d_in[2];
  const float* W1  = (const float*)d_in[3];
  const float* b1  = (const float*)d_in[4];
  const float* W2  = (const float*)d_in[5];
  const float* b2  = (const float*)d_in[6];
  float* out = (float*)d_out;
  char* ws   = (char*)d_ws;               // 1MB G1 + 48KB packed fragments

  k_prep<<<1036, 256, 0, stream>>>(gf, W1, b1, W2, ws);
  k_main<<<NMLP + NCOPY, 256, 0, stream>>>(x, pidx, b2, ws, out);
}

// Round 13
// 146.911 us; speedup vs baseline: 6.2625x; 1.1407x over previous
//
#include <hip/hip_runtime.h>
#include <hip/hip_bf16.h>

#define BATCH   2048
#define NPAR    256
#define NF      32
#define NG      16
#define NBR     4
#define OFS     262144
#define DOUT    128
#define NROWSX  (OFS + NPAR*BATCH)     // 786432 rows of x
#define MROWS   (NPAR*BATCH)           // 524288 parent rows
#define CHBASE  (NROWSX*NF)            // float offset of children region in out
#define NMLP    4096                   // MLP blocks: 8 waves x 1 tile each
#define NCOPY   2048                   // copy blocks
#define CPN4    (NROWSX*NF/4)          // 6291456 float4 to copy

typedef short bf16x8 __attribute__((ext_vector_type(8)));   // 8 bf16 bit-patterns
typedef float f32x4  __attribute__((ext_vector_type(4)));

// ws layout (bytes): [0,1MB) G1 f32 | +32KB W2frag | +8KB W1frag | +8KB Rfrag
#define WSOFF_W2F  1048576
#define WSOFF_W1F  (1048576 + 32768)
#define WSOFF_RF   (1048576 + 32768 + 8192)

__device__ __forceinline__ unsigned short f2bf(float f){
  unsigned int u = __float_as_uint(f);
  u += 0x7FFFu + ((u >> 16) & 1u);          // RNE
  return (unsigned short)(u >> 16);
}

// blocks [0,1024): G1[e][j] = b1[j] + sum_k global[e][k] * W1[32+k][j]
// blocks [1024,1036): pack W2 / W1-feature-half / repeat-matrix R fragments.
// W2 fragments use the k-slot permutation sigma(8g+e) = (e<4 ? 4g+e
// : 16+4g+e-4) so GEMM2's A-operand is a direct register repack of acc1
// (no LDS round-trip). MFMA is invariant when BOTH operands share sigma.
__global__ void k_prep(const float* __restrict__ gf, const float* __restrict__ W1,
                       const float* __restrict__ b1, const float* __restrict__ W2,
                       char* __restrict__ ws){
  int bid = blockIdx.x, tid = threadIdx.x;
  if (bid < 1024){
    int idx = bid*256 + tid;
    int e = idx >> 7, j = idx & 127;
    float s = b1[j];
    const float* grow = gf + e*NG;
    const float* w = W1 + NF*DOUT + j;
    #pragma unroll
    for (int k = 0; k < NG; k++) s = fmaf(grow[k], w[k*DOUT], s);
    ((float*)ws)[idx] = s;
    return;
  }
  int t = (bid - 1024)*256 + tid;          // 0..3071
  if (t < 2048){
    // W2 fragment uint4 t: f = t>>6 (kk*8+n), lane l = t&63
    int f = t >> 6, l = t & 63;
    int kk = f >> 3, n = f & 7;
    int g4  = 4*(l >> 4);
    int col = 16*n + (l & 15);
    union { uint4 q; unsigned short u[8]; } w;
    #pragma unroll
    for (int e = 0; e < 8; e++){
      int krow = 32*kk + (e < 4 ? g4 + e : 16 + g4 + (e - 4));   // sigma
      w.u[e] = f2bf(W2[krow*DOUT + col]);
    }
    ((uint4*)(ws + WSOFF_W2F))[t] = w.q;
  } else if (t < 2560){
    int q = t - 2048;                      // 0..511: W1 feature-half fragments
    int n = q >> 6, l = q & 63;
    int kb = 8*(l >> 4);
    int col = 16*n + (l & 15);
    union { uint4 v; unsigned short u[8]; } w;
    #pragma unroll
    for (int e = 0; e < 8; e++) w.u[e] = f2bf(W1[(kb + e)*DOUT + col]);
    ((uint4*)(ws + WSOFF_W1F))[q] = w.v;
  } else {
    // R fragments: A[r][k] = 1 iff k == 4n + (r>>2)  (repeat_interleave matrix)
    int q = t - 2560;                      // 0..511
    int n = q >> 6, l = q & 63;
    int g = l >> 4, r = l & 15;
    int e1 = 4*n + (r >> 2) - 8*g;
    union { uint4 v; unsigned short u[8]; } w;
    #pragma unroll
    for (int e = 0; e < 8; e++) w.u[e] = (e == e1) ? 0x3F80 : 0;
    ((uint4*)(ws + WSOFF_RF))[q] = w.v;
  }
}

// Main kernel, 512 threads, NO occupancy hints. 48 KB LDS -> 3 blocks/CU.
// bid%3==2 -> pure copy block; else MLP block (8 waves x 1 tile each).
__global__ void k_main(
    const float* __restrict__ x, const int* __restrict__ pidx,
    const float* __restrict__ b2, const char* __restrict__ ws,
    float* __restrict__ out)
{
  __shared__ uint4 sB2[2048];   // 32 KB: W2 B-fragments [frag(kk*8+n)][lane]
  __shared__ uint4 sWR[1024];   // 16 KB: [0,512) W1 frags, [512,1024) R frags

  const int bid = blockIdx.x;
  const int tid = threadIdx.x;

  if (bid % 3 == 2){
    // ---- copy path: out[0:NROWSX*NF] = x, pure bandwidth, free-running ----
    const int cid = bid / 3;                      // 0..NCOPY-1
    const float4* src4 = (const float4*)x;
    float4* dst4 = (float4*)out;
    for (int i = cid*512 + tid; i < CPN4; i += NCOPY*512)
      dst4[i] = src4[i];
    return;
  }
  const int mid = (bid/3)*2 + (bid % 3);          // 0..NMLP-1

  // ---- stage pre-packed fragments into LDS (6 x 16B per thread) ----
  const uint4* W2f = (const uint4*)(ws + WSOFF_W2F);
  const uint4* WRf = (const uint4*)(ws + WSOFF_W1F);  // W1+R contiguous, 1024
  #pragma unroll
  for (int i = 0; i < 4; i++) sB2[i*512 + tid] = W2f[i*512 + tid];
  sWR[tid] = WRf[tid];                   // W1 fragments
  sWR[512 + tid] = WRf[512 + tid];       // R fragments
  __syncthreads();

  const int lane = tid & 63;
  const int wv   = tid >> 6;
  const int r15  = lane & 15;
  const int g    = lane >> 4;
  const float* G1 = (const float*)ws;

  const bf16x8* B2f = (const bf16x8*)sB2;
  const bf16x8* B1f = (const bf16x8*)sWR;          // frags 0..7
  const bf16x8* Rf  = (const bf16x8*)(sWR + 512);  // frags 0..7

  const int tl   = mid*8 + wv;             // tile index (one per wave)
  const int row0 = tl*16;

  // This lane's batch row within the tile is r15 (transposed layout).
  const int idxA = pidx[row0 + r15];

  // x row: A/B fragment source (cols 8g..8g+7)
  const float* ap = x + idxA*NF + 8*g;
  float4 a0 = *(const float4*)ap;
  float4 a1 = *(const float4*)(ap + 4);

  // GEMM1 acc init: G1 row (bias + global half folded in), float4 loads
  const int g1r = idxA & (BATCH-1);
  f32x4 acc1[8];
  #pragma unroll
  for (int n = 0; n < 8; n++)
    acc1[n] = *(const f32x4*)(G1 + g1r*DOUT + 16*n + 4*g);

  // convert A-fragment
  union { bf16x8 v; __hip_bfloat162 h[4]; } af;
  af.h[0] = __float22bfloat162_rn(make_float2(a0.x, a0.y));
  af.h[1] = __float22bfloat162_rn(make_float2(a0.z, a0.w));
  af.h[2] = __float22bfloat162_rn(make_float2(a1.x, a1.y));
  af.h[3] = __float22bfloat162_rn(make_float2(a1.z, a1.w));

  // GEMM1 (transposed): acc1[n][r] = h1[row_r15][16n+4g+r]
  #pragma unroll
  for (int n = 0; n < 8; n++)
    acc1[n] = __builtin_amdgcn_mfma_f32_16x16x32_bf16(B1f[n*64 + lane], af.v, acc1[n], 0, 0, 0);

  // leaky-relu + pack to bf16 pairs, all in registers
  __hip_bfloat162 pa[8][2];
  #pragma unroll
  for (int n = 0; n < 8; n++){
    float v0 = acc1[n][0], v1 = acc1[n][1], v2 = acc1[n][2], v3 = acc1[n][3];
    v0 = v0 > 0.f ? v0 : 0.01f*v0;
    v1 = v1 > 0.f ? v1 : 0.01f*v1;
    v2 = v2 > 0.f ? v2 : 0.01f*v2;
    v3 = v3 > 0.f ? v3 : 0.01f*v3;
    pa[n][0] = __float22bfloat162_rn(make_float2(v0, v1));
    pa[n][1] = __float22bfloat162_rn(make_float2(v2, v3));
  }

  // GEMM2: b2 folded into init, residual folded in via R-fragment MFMA.
  // A-operand for MFMA kk = {acc1[2kk], acc1[2kk+1]} packed — the sigma
  // permutation baked into the W2 fragments makes this exact (no LDS).
  f32x4 acc2[8];
  #pragma unroll
  for (int n = 0; n < 8; n++)
    acc2[n] = *(const f32x4*)(b2 + 16*n + 4*g);
  #pragma unroll
  for (int n = 0; n < 8; n++)
    acc2[n] = __builtin_amdgcn_mfma_f32_16x16x32_bf16(Rf[n*64 + lane], af.v, acc2[n], 0, 0, 0);
  #pragma unroll
  for (int kk = 0; kk < 4; kk++){
    union { bf16x8 v; __hip_bfloat162 h[4]; } a2;
    a2.h[0] = pa[2*kk][0];   a2.h[1] = pa[2*kk][1];
    a2.h[2] = pa[2*kk+1][0]; a2.h[3] = pa[2*kk+1][1];
    #pragma unroll
    for (int n = 0; n < 8; n++)
      acc2[n] = __builtin_amdgcn_mfma_f32_16x16x32_bf16(B2f[(kk*8 + n)*64 + lane], a2.v, acc2[n], 0, 0, 0);
  }

  // epilogue: pure float4 stores to children layout (no trailing loads)
  const int p  = row0 >> 11;               // parent (tiles never cross parents)
  const int b0 = row0 & (BATCH-1);
  const int orow = CHBASE + ((p*NBR)*BATCH + b0 + r15)*NF;
  #pragma unroll
  for (int n = 0; n < 8; n++){
    int c0 = 16*n + 4*g;                   // first of 4 consecutive output cols
    int br = c0 >> 5, fc0 = c0 & 31;
    *(f32x4*)(out + orow + br*(BATCH*NF) + fc0) = acc2[n];
  }
}

extern "C" void kernel_launch(void* const* d_in, const int* in_sizes, int n_in,
                              void* d_out, int out_size, void* d_ws, size_t ws_size,
                              hipStream_t stream){
  const float* x   = (const float*)d_in[0];
  const float* gf  = (const float*)d_in[1];
  const int*   pidx= (const int*)d_in[2];
  const float* W1  = (const float*)d_in[3];
  const float* b1  = (const float*)d_in[4];
  const float* W2  = (const float*)d_in[5];
  const float* b2  = (const float*)d_in[6];
  float* out = (float*)d_out;
  char* ws   = (char*)d_ws;               // 1MB G1 + 48KB packed fragments

  k_prep<<<1036, 256, 0, stream>>>(gf, W1, b1, W2, ws);
  k_main<<<NMLP + NCOPY, 512, 0, stream>>>(x, pidx, b2, ws, out);
}